// Round 1
// baseline (3309.777 us; speedup 1.0000x reference)
//
#include <hip/hip_runtime.h>
#include <math.h>

#define BB 8
#define SS 1024
#define HH 2048
#define NQH 32
#define NKVH 8
#define DD 64
#define MROWS (BB*SS)   // 8192

// ---------------------------------------------------------------------------
// fp32 GEMM: C[M,N] = A[M,K] * B[K,N], row-major. 128x128x16 tile, 256 thr,
// 8x8 register tile per thread. M%128==0, N%128==0, K%16==0.
// ---------------------------------------------------------------------------
__global__ __launch_bounds__(256) void gemm_f32_128(
    const float* __restrict__ A, const float* __restrict__ Bm,
    float* __restrict__ C, int M, int N, int K)
{
    __shared__ float As[16][128];   // [k][m] (transposed)
    __shared__ float Bs[16][128];   // [k][n]
    const int tid = threadIdx.x;
    const int bm = blockIdx.y * 128;
    const int bn = blockIdx.x * 128;
    const int ty = tid >> 4, tx = tid & 15;

    alignas(16) float acc[8][8];
    #pragma unroll
    for (int i = 0; i < 8; ++i)
        #pragma unroll
        for (int j = 0; j < 8; ++j) acc[i][j] = 0.f;

    for (int k0 = 0; k0 < K; k0 += 16) {
        // A tile: 128 rows x 16 k, float4 along k, store transposed
        #pragma unroll
        for (int p = 0; p < 2; ++p) {
            int m  = p * 64 + (tid >> 2);
            int kq = (tid & 3) << 2;
            float4 a = *reinterpret_cast<const float4*>(A + (size_t)(bm + m) * K + k0 + kq);
            As[kq + 0][m] = a.x; As[kq + 1][m] = a.y;
            As[kq + 2][m] = a.z; As[kq + 3][m] = a.w;
        }
        // B tile: 16 k x 128 n, float4 along n
        #pragma unroll
        for (int p = 0; p < 2; ++p) {
            int idx = p * 256 + tid;
            int kr  = idx >> 5;
            int nq  = (idx & 31) << 2;
            *reinterpret_cast<float4*>(&Bs[kr][nq]) =
                *reinterpret_cast<const float4*>(Bm + (size_t)(k0 + kr) * N + bn + nq);
        }
        __syncthreads();
        #pragma unroll
        for (int kk = 0; kk < 16; ++kk) {
            alignas(16) float a[8], b[8];
            *(float4*)&a[0] = *(const float4*)&As[kk][ty * 8];
            *(float4*)&a[4] = *(const float4*)&As[kk][ty * 8 + 4];
            *(float4*)&b[0] = *(const float4*)&Bs[kk][tx * 8];
            *(float4*)&b[4] = *(const float4*)&Bs[kk][tx * 8 + 4];
            #pragma unroll
            for (int i = 0; i < 8; ++i)
                #pragma unroll
                for (int j = 0; j < 8; ++j)
                    acc[i][j] = fmaf(a[i], b[j], acc[i][j]);
        }
        __syncthreads();
    }
    #pragma unroll
    for (int i = 0; i < 8; ++i) {
        float* crow = C + (size_t)(bm + ty * 8 + i) * N + bn + tx * 8;
        *(float4*)crow       = *(const float4*)&acc[i][0];
        *(float4*)(crow + 4) = *(const float4*)&acc[i][4];
    }
}

// ---------------------------------------------------------------------------
// RoPE in-place on Q [8192, 32, 64] and K [8192, 8, 64].
// One thread per (row, head, pair j<32).
// out[j]    = x[j]*cos(t*f_j) - x[j+32]*sin(t*f_j)
// out[j+32] = x[j+32]*cos(t*f_j) + x[j]*sin(t*f_j),  f_j = 10000^(-j/32)
// ---------------------------------------------------------------------------
__global__ void rope_f32(float* __restrict__ Qw, float* __restrict__ Kw)
{
    const int totQ = MROWS * NQH * 32;
    const int totK = MROWS * NKVH * 32;
    int idx = blockIdx.x * 256 + threadIdx.x;
    float* x;
    int j, row;
    if (idx < totQ) {
        j = idx & 31;
        int hd = idx >> 5;           // row*NQH + head
        x = Qw + (size_t)hd * DD;
        row = hd >> 5;               // /NQH
    } else {
        idx -= totQ;
        if (idx >= totK) return;
        j = idx & 31;
        int hd = idx >> 5;           // row*NKVH + head
        x = Kw + (size_t)hd * DD;
        row = hd >> 3;               // /NKVH
    }
    int pos = row & (SS - 1);
    // ln(10000)/32 = 0.28782313662
    float ang = (float)pos * __expf(-(float)j * 0.28782314f);
    float s, c;
    __sincosf(ang, &s, &c);
    float x1 = x[j], x2 = x[j + 32];
    x[j]      = x1 * c - x2 * s;
    x[j + 32] = x2 * c + x1 * s;
}

// ---------------------------------------------------------------------------
// Causal GQA flash attention, fp32.
// Grid: (S/64, NQ, B). Block 256 threads = 16x16 (ty,tx), 4x4 register tiles.
// Q/K stored transposed in LDS ([d][row]) for conflict-free float4 reads.
// O is written in-place over Q (each block reads only its own Q tile first).
// ---------------------------------------------------------------------------
__global__ __launch_bounds__(256) void attn_f32(
    const float* __restrict__ Qg, const float* __restrict__ Kg,
    const float* __restrict__ Vg, float* __restrict__ Og)
{
    const int qt = blockIdx.x;
    const int h  = blockIdx.y;
    const int b  = blockIdx.z;
    const int hk = h >> 2;               // NQ/NKV = 4
    const int tid = threadIdx.x;
    const int ty = tid >> 4, tx = tid & 15;

    __shared__ float Qs[64][64];         // [d][i]
    __shared__ float Ks[64][64];         // [d][j]
    __shared__ float Vs[64][64];         // [j][d^swz]
    __shared__ float Ps[64][65];         // [i][j], padded

    // load Q tile transposed
    {
        int i  = tid >> 2;
        int dq = (tid & 3) << 4;
        const float* src = Qg + ((size_t)(b * SS + qt * 64 + i) * NQH + h) * DD + dq;
        #pragma unroll
        for (int t = 0; t < 4; ++t) {
            float4 v = *reinterpret_cast<const float4*>(src + t * 4);
            int d0 = dq + t * 4;
            Qs[d0 + 0][i] = v.x; Qs[d0 + 1][i] = v.y;
            Qs[d0 + 2][i] = v.z; Qs[d0 + 3][i] = v.w;
        }
    }

    alignas(16) float acc[4][4];
    #pragma unroll
    for (int i = 0; i < 4; ++i)
        #pragma unroll
        for (int j = 0; j < 4; ++j) acc[i][j] = 0.f;
    float m_run[4], l_run[4];
    #pragma unroll
    for (int i = 0; i < 4; ++i) { m_run[i] = -INFINITY; l_run[i] = 0.f; }

    for (int kt = 0; kt <= qt; ++kt) {
        __syncthreads();   // previous iteration's PV reads done before overwrite
        {
            int j  = tid >> 2;
            int dq = (tid & 3) << 4;
            const float* ksrc = Kg + ((size_t)(b * SS + kt * 64 + j) * NKVH + hk) * DD + dq;
            const float* vsrc = Vg + ((size_t)(b * SS + kt * 64 + j) * NKVH + hk) * DD + dq;
            #pragma unroll
            for (int t = 0; t < 4; ++t) {
                int d0 = dq + t * 4;
                float4 v = *reinterpret_cast<const float4*>(ksrc + t * 4);
                Ks[d0 + 0][j] = v.x; Ks[d0 + 1][j] = v.y;
                Ks[d0 + 2][j] = v.z; Ks[d0 + 3][j] = v.w;
                float4 w = *reinterpret_cast<const float4*>(vsrc + t * 4);
                *reinterpret_cast<float4*>(&Vs[j][d0 ^ ((j & 7) << 2)]) = w;
            }
        }
        __syncthreads();

        // S = Q K^T (4x4 per thread)
        alignas(16) float s[4][4];
        #pragma unroll
        for (int i = 0; i < 4; ++i)
            #pragma unroll
            for (int j = 0; j < 4; ++j) s[i][j] = 0.f;
        #pragma unroll 8
        for (int d = 0; d < 64; ++d) {
            alignas(16) float a[4], bb[4];
            *(float4*)a  = *(const float4*)&Qs[d][ty << 2];
            *(float4*)bb = *(const float4*)&Ks[d][tx << 2];
            #pragma unroll
            for (int ii = 0; ii < 4; ++ii)
                #pragma unroll
                for (int jj = 0; jj < 4; ++jj)
                    s[ii][jj] = fmaf(a[ii], bb[jj], s[ii][jj]);
        }
        #pragma unroll
        for (int ii = 0; ii < 4; ++ii)
            #pragma unroll
            for (int jj = 0; jj < 4; ++jj) s[ii][jj] *= 0.125f;  // 1/sqrt(64)

        if (kt == qt) {   // causal mask on diagonal tile
            #pragma unroll
            for (int ii = 0; ii < 4; ++ii)
                #pragma unroll
                for (int jj = 0; jj < 4; ++jj)
                    if ((tx << 2) + jj > (ty << 2) + ii) s[ii][jj] = -INFINITY;
        }

        // online softmax update; row reduce across the 16 tx lanes
        #pragma unroll
        for (int ii = 0; ii < 4; ++ii) {
            float mx = fmaxf(fmaxf(s[ii][0], s[ii][1]), fmaxf(s[ii][2], s[ii][3]));
            #pragma unroll
            for (int st = 1; st < 16; st <<= 1)
                mx = fmaxf(mx, __shfl_xor(mx, st, 64));
            float mnew = fmaxf(m_run[ii], mx);
            float corr = __expf(m_run[ii] - mnew);   // exp(-inf)=0 on first tile
            float ps = 0.f;
            #pragma unroll
            for (int jj = 0; jj < 4; ++jj) {
                float p = __expf(s[ii][jj] - mnew);  // masked -> exp(-inf)=0
                ps += p;
                Ps[(ty << 2) + ii][(tx << 2) + jj] = p;
            }
            #pragma unroll
            for (int st = 1; st < 16; st <<= 1)
                ps += __shfl_xor(ps, st, 64);
            l_run[ii] = l_run[ii] * corr + ps;
            m_run[ii] = mnew;
            #pragma unroll
            for (int dd = 0; dd < 4; ++dd) acc[ii][dd] *= corr;
        }
        __syncthreads();   // P complete before PV

        // O += P V
        #pragma unroll 4
        for (int j = 0; j < 64; ++j) {
            float a0 = Ps[(ty << 2) + 0][j];
            float a1 = Ps[(ty << 2) + 1][j];
            float a2 = Ps[(ty << 2) + 2][j];
            float a3 = Ps[(ty << 2) + 3][j];
            float4 bv = *(const float4*)&Vs[j][(tx << 2) ^ ((j & 7) << 2)];
            acc[0][0] = fmaf(a0, bv.x, acc[0][0]); acc[0][1] = fmaf(a0, bv.y, acc[0][1]);
            acc[0][2] = fmaf(a0, bv.z, acc[0][2]); acc[0][3] = fmaf(a0, bv.w, acc[0][3]);
            acc[1][0] = fmaf(a1, bv.x, acc[1][0]); acc[1][1] = fmaf(a1, bv.y, acc[1][1]);
            acc[1][2] = fmaf(a1, bv.z, acc[1][2]); acc[1][3] = fmaf(a1, bv.w, acc[1][3]);
            acc[2][0] = fmaf(a2, bv.x, acc[2][0]); acc[2][1] = fmaf(a2, bv.y, acc[2][1]);
            acc[2][2] = fmaf(a2, bv.z, acc[2][2]); acc[2][3] = fmaf(a2, bv.w, acc[2][3]);
            acc[3][0] = fmaf(a3, bv.x, acc[3][0]); acc[3][1] = fmaf(a3, bv.y, acc[3][1]);
            acc[3][2] = fmaf(a3, bv.z, acc[3][2]); acc[3][3] = fmaf(a3, bv.w, acc[3][3]);
        }
    }

    // epilogue: O = acc / l, write in-place over Q region
    #pragma unroll
    for (int ii = 0; ii < 4; ++ii) {
        float inv = 1.f / l_run[ii];
        alignas(16) float o[4];
        #pragma unroll
        for (int dd = 0; dd < 4; ++dd) o[dd] = acc[ii][dd] * inv;
        float* dst = Og + ((size_t)(b * SS + qt * 64 + (ty << 2) + ii) * NQH + h) * DD + (tx << 2);
        *(float4*)dst = *(const float4*)o;
    }
}

// ---------------------------------------------------------------------------
extern "C" void kernel_launch(void* const* d_in, const int* in_sizes, int n_in,
                              void* d_out, int out_size, void* d_ws, size_t ws_size,
                              hipStream_t stream)
{
    const float* X  = (const float*)d_in[0];
    const float* Wq = (const float*)d_in[1];
    const float* Wk = (const float*)d_in[2];
    const float* Wv = (const float*)d_in[3];
    const float* Wo = (const float*)d_in[4];
    float* out = (float*)d_out;

    // workspace: Q (8192x2048, reused as attention output), K, V (8192x512 each)
    float* Qw = (float*)d_ws;
    float* Kw = Qw + (size_t)MROWS * (NQH * DD);
    float* Vw = Kw + (size_t)MROWS * (NKVH * DD);

    dim3 blk(256);
    gemm_f32_128<<<dim3((NQH * DD) / 128,  MROWS / 128), blk, 0, stream>>>(X, Wq, Qw, MROWS, NQH * DD,  HH);
    gemm_f32_128<<<dim3((NKVH * DD) / 128, MROWS / 128), blk, 0, stream>>>(X, Wk, Kw, MROWS, NKVH * DD, HH);
    gemm_f32_128<<<dim3((NKVH * DD) / 128, MROWS / 128), blk, 0, stream>>>(X, Wv, Vw, MROWS, NKVH * DD, HH);

    int ropeTotal = MROWS * NQH * 32 + MROWS * NKVH * 32;
    rope_f32<<<ropeTotal / 256, blk, 0, stream>>>(Qw, Kw);

    attn_f32<<<dim3(SS / 64, NQH, BB), blk, 0, stream>>>(Qw, Kw, Vw, Qw);

    gemm_f32_128<<<dim3(HH / 128, MROWS / 128), blk, 0, stream>>>(Qw, Wo, out, MROWS, HH, NQH * DD);
}

// Round 2
// 827.613 us; speedup vs baseline: 3.9992x; 3.9992x over previous
//
#include <hip/hip_runtime.h>
#include <math.h>

#define BB 8
#define SS 1024
#define HH 2048
#define NQH 32
#define NKVH 8
#define DD 64
#define MROWS (BB*SS)   // 8192

typedef __attribute__((ext_vector_type(8))) short bf16x8;   // 8 bf16 in 4 VGPRs
typedef __attribute__((ext_vector_type(4))) float f32x4;

__device__ __forceinline__ unsigned short f2bf(float x) {
    unsigned int u = __float_as_uint(x);
    unsigned int r = (u + 0x7FFFu + ((u >> 16) & 1u)) >> 16;   // RNE
    return (unsigned short)r;
}
__device__ __forceinline__ float bf2f(unsigned short u) {
    return __uint_as_float(((unsigned int)u) << 16);
}

__device__ __forceinline__ void gload_lds16(const void* gsrc, void* ldst) {
    __builtin_amdgcn_global_load_lds(
        (const __attribute__((address_space(1))) unsigned int*)gsrc,
        (__attribute__((address_space(3))) unsigned int*)ldst,
        16, 0, 0);
}

// ---------------------------------------------------------------------------
// fp32 -> bf16 elementwise convert, 8 elements/thread
// ---------------------------------------------------------------------------
__global__ void conv_bf16(const float* __restrict__ src,
                          unsigned short* __restrict__ dst, int n8)
{
    int i = blockIdx.x * 256 + threadIdx.x;
    if (i >= n8) return;
    const float4* s4 = (const float4*)src;
    float4 a = s4[i * 2], b = s4[i * 2 + 1];
    bf16x8 o;
    o[0] = (short)f2bf(a.x); o[1] = (short)f2bf(a.y);
    o[2] = (short)f2bf(a.z); o[3] = (short)f2bf(a.w);
    o[4] = (short)f2bf(b.x); o[5] = (short)f2bf(b.y);
    o[6] = (short)f2bf(b.z); o[7] = (short)f2bf(b.w);
    *(bf16x8*)(dst + (size_t)i * 8) = o;
}

// ---------------------------------------------------------------------------
// W [K][N] fp32  ->  WT [N][K] bf16  (64x64 tiles via LDS)
// ---------------------------------------------------------------------------
__global__ __launch_bounds__(256) void transpose_conv(
    const float* __restrict__ W, unsigned short* __restrict__ WT, int K, int N)
{
    __shared__ unsigned short t[64][68];
    const int bn = blockIdx.x * 64;   // W col tile = WT row tile
    const int bk = blockIdx.y * 64;   // W row tile
    #pragma unroll
    for (int it = 0; it < 4; ++it) {
        int idx = it * 256 + threadIdx.x;
        int r  = idx >> 4;            // k row 0..63
        int cq = (idx & 15) * 4;      // n col
        float4 v = *(const float4*)(W + (size_t)(bk + r) * N + bn + cq);
        t[cq + 0][r] = f2bf(v.x);
        t[cq + 1][r] = f2bf(v.y);
        t[cq + 2][r] = f2bf(v.z);
        t[cq + 3][r] = f2bf(v.w);
    }
    __syncthreads();
    #pragma unroll
    for (int it = 0; it < 4; ++it) {
        int idx = it * 256 + threadIdx.x;
        int r  = idx >> 4;            // n row 0..63
        int cq = (idx & 15) * 4;      // k col
        ushort4 o;
        o.x = t[r][cq + 0]; o.y = t[r][cq + 1];
        o.z = t[r][cq + 2]; o.w = t[r][cq + 3];
        *(ushort4*)(WT + (size_t)(bn + r) * K + bk + cq) = o;
    }
}

// ---------------------------------------------------------------------------
// bf16 MFMA GEMM (m97 structure): C[M,N] = A[M,K] * Bt[N,K]^T
// 128x128 tile, BK=32, 4 waves (2x2), 4x4 16x16x32 fragments per wave,
// global_load_lds width-16 staging, fp32 accumulate, OutT output.
// ---------------------------------------------------------------------------
template <typename OutT>
__global__ __launch_bounds__(256) void gemm_bf16(
    const unsigned short* __restrict__ A,    // [M][K] bf16
    const unsigned short* __restrict__ Bt,   // [N][K] bf16
    OutT* __restrict__ C, int M, int N, int K)
{
    __shared__ __align__(16) unsigned short As[128 * 32];
    __shared__ __align__(16) unsigned short Bs[128 * 32];
    const int tid = threadIdx.x;
    const int lane = tid & 63;
    const int w = tid >> 6;
    const int wr = w >> 1, wc = w & 1;
    const int l15 = lane & 15, lg = lane >> 4;
    const int bm = blockIdx.y * 128, bn = blockIdx.x * 128;

    f32x4 acc[4][4] = {};

    for (int k0 = 0; k0 < K; k0 += 32) {
        #pragma unroll
        for (int t = 0; t < 2; ++t) {
            int lin = t * 256 + tid;
            int row = lin >> 2, cg = lin & 3;
            gload_lds16(A  + (size_t)(bm + row) * K + k0 + cg * 8, As + (size_t)lin * 8);
            gload_lds16(Bt + (size_t)(bn + row) * K + k0 + cg * 8, Bs + (size_t)lin * 8);
        }
        __syncthreads();
        bf16x8 af[4], bfr[4];
        #pragma unroll
        for (int m = 0; m < 4; ++m)
            af[m] = *(const bf16x8*)(As + (wr * 64 + m * 16 + l15) * 32 + lg * 8);
        #pragma unroll
        for (int n = 0; n < 4; ++n)
            bfr[n] = *(const bf16x8*)(Bs + (wc * 64 + n * 16 + l15) * 32 + lg * 8);
        #pragma unroll
        for (int m = 0; m < 4; ++m)
            #pragma unroll
            for (int n = 0; n < 4; ++n)
                acc[m][n] = __builtin_amdgcn_mfma_f32_16x16x32_bf16(
                    af[m], bfr[n], acc[m][n], 0, 0, 0);
        __syncthreads();
    }

    #pragma unroll
    for (int m = 0; m < 4; ++m) {
        int row0 = bm + wr * 64 + m * 16 + lg * 4;
        #pragma unroll
        for (int n = 0; n < 4; ++n) {
            int col = bn + wc * 64 + n * 16 + l15;
            #pragma unroll
            for (int r = 0; r < 4; ++r) {
                float v = acc[m][n][r];
                if constexpr (sizeof(OutT) == 2)
                    C[(size_t)(row0 + r) * N + col] = (OutT)f2bf(v);
                else
                    C[(size_t)(row0 + r) * N + col] = v;
            }
        }
    }
}

// ---------------------------------------------------------------------------
// RoPE in-place, bf16. Q [8192][2048] stride 2048; K in KV [8192][1024] cols 0-511.
// ---------------------------------------------------------------------------
__global__ void rope_bf16(unsigned short* __restrict__ Q,
                          unsigned short* __restrict__ KV)
{
    int idx = blockIdx.x * 256 + threadIdx.x;
    const int totQ = MROWS * NQH * 32;
    unsigned short* x;
    int j, pos;
    if (idx < totQ) {
        j = idx & 31;
        int hd = idx >> 5;                // row*32 + head
        x = Q + (size_t)hd * 64;
        pos = (hd >> 5) & (SS - 1);
    } else {
        idx -= totQ;
        j = idx & 31;
        int hd = idx >> 5;                // row*8 + head
        int row = hd >> 3, head = hd & 7;
        x = KV + (size_t)row * 1024 + head * 64;
        pos = row & (SS - 1);
    }
    // f_j = 10000^(-j/32);  ln(10000)/32 = 0.28782313662
    float ang = (float)pos * __expf(-(float)j * 0.28782314f);
    float s, c;
    __sincosf(ang, &s, &c);
    float x1 = bf2f(x[j]), x2 = bf2f(x[j + 32]);
    x[j]      = f2bf(x1 * c - x2 * s);
    x[j + 32] = f2bf(x2 * c + x1 * s);
}

// ---------------------------------------------------------------------------
// Causal GQA flash attention, bf16 MFMA. Grid (S/64, NQ, B), 256 threads = 4 waves.
// Wave w owns q-rows 16w..16w+15 of the 64-row tile. KVBLK=64.
// Q fragments direct from global; K fragments direct from global (L2-hot);
// V transposed into LDS [d][key] stride 72; P via per-wave LDS [16][72].
// Output written in-place over Q.
// ---------------------------------------------------------------------------
__global__ __launch_bounds__(256) void attn_bf16(
    unsigned short* Q,                 // [B*S][2048], also output
    const unsigned short* KV)          // [B*S][1024]: 0-511 K, 512-1023 V
{
    const int qt = blockIdx.x, h = blockIdx.y, b = blockIdx.z;
    const int hk = h >> 2;
    const int tid = threadIdx.x;
    const int w = tid >> 6, lane = tid & 63;
    const int l15 = lane & 15, lg = lane >> 4;

    __shared__ __align__(16) unsigned short VT[64 * 72];      // [d][key]
    __shared__ __align__(16) unsigned short Pl[4][16 * 72];   // per-wave [row][key]

    unsigned short* qbase = Q + (size_t)(b * SS + qt * 64 + w * 16 + l15) * (NQH * DD) + h * DD;
    bf16x8 qf[2];
    qf[0] = *(const bf16x8*)(qbase + lg * 8);
    qf[1] = *(const bf16x8*)(qbase + 32 + lg * 8);

    f32x4 acc_o[4] = {};
    float m_run[4], l_run[4];
    #pragma unroll
    for (int r = 0; r < 4; ++r) { m_run[r] = -INFINITY; l_run[r] = 0.f; }

    const int vkey = tid & 63, vd0 = (tid >> 6) * 16;

    for (int kt = 0; kt <= qt; ++kt) {
        __syncthreads();   // prev PV reads of VT done
        // stage V^T: thread handles key=vkey, d = vd0..vd0+15
        {
            const unsigned short* vrow =
                KV + (size_t)(b * SS + kt * 64 + vkey) * 1024 + 512 + hk * DD + vd0;
            #pragma unroll
            for (int u = 0; u < 2; ++u) {
                bf16x8 vv = *(const bf16x8*)(vrow + u * 8);
                #pragma unroll
                for (int i2 = 0; i2 < 8; ++i2)
                    VT[(vd0 + u * 8 + i2) * 72 + vkey] = (unsigned short)vv[i2];
            }
        }
        // S = Q K^T : K fragments straight from global (L2-hot)
        const unsigned short* kbase = KV + (size_t)(b * SS + kt * 64) * 1024 + hk * DD;
        f32x4 sa[4] = {};
        #pragma unroll
        for (int n = 0; n < 4; ++n) {
            #pragma unroll
            for (int kk = 0; kk < 2; ++kk) {
                bf16x8 kf = *(const bf16x8*)(kbase + (size_t)(n * 16 + l15) * 1024 + kk * 32 + lg * 8);
                sa[n] = __builtin_amdgcn_mfma_f32_16x16x32_bf16(qf[kk], kf, sa[n], 0, 0, 0);
            }
        }
        __syncthreads();   // VT writes complete

        // online softmax (fp32). Lane holds: key col = 16n + l15, q rows = 4*lg + r.
        float sv[4][4];
        #pragma unroll
        for (int n = 0; n < 4; ++n)
            #pragma unroll
            for (int r = 0; r < 4; ++r) {
                float v = sa[n][r] * 0.125f;     // 1/sqrt(64)
                if (kt == qt) {
                    int keyl = n * 16 + l15;
                    int qrl  = w * 16 + lg * 4 + r;
                    if (keyl > qrl) v = -INFINITY;
                }
                sv[n][r] = v;
            }
        #pragma unroll
        for (int r = 0; r < 4; ++r) {
            float mx = fmaxf(fmaxf(sv[0][r], sv[1][r]), fmaxf(sv[2][r], sv[3][r]));
            #pragma unroll
            for (int st = 1; st < 16; st <<= 1) mx = fmaxf(mx, __shfl_xor(mx, st));
            float mnew = fmaxf(m_run[r], mx);
            float corr = __expf(m_run[r] - mnew);
            float ps = 0.f;
            #pragma unroll
            for (int n = 0; n < 4; ++n) {
                float p = __expf(sv[n][r] - mnew);
                ps += p;
                Pl[w][(lg * 4 + r) * 72 + n * 16 + l15] = f2bf(p);
            }
            #pragma unroll
            for (int st = 1; st < 16; st <<= 1) ps += __shfl_xor(ps, st);
            l_run[r] = l_run[r] * corr + ps;
            m_run[r] = mnew;
            #pragma unroll
            for (int m = 0; m < 4; ++m) acc_o[m][r] *= corr;
        }

        // O += P V  (A = P rows from private LDS, B = V^T from LDS)
        #pragma unroll
        for (int ks = 0; ks < 2; ++ks) {
            bf16x8 pa = *(const bf16x8*)(&Pl[w][l15 * 72 + ks * 32 + lg * 8]);
            #pragma unroll
            for (int m = 0; m < 4; ++m) {
                bf16x8 vb = *(const bf16x8*)(&VT[(m * 16 + l15) * 72 + ks * 32 + lg * 8]);
                acc_o[m] = __builtin_amdgcn_mfma_f32_16x16x32_bf16(pa, vb, acc_o[m], 0, 0, 0);
            }
        }
    }

    // epilogue: O = acc / l, in-place over Q
    #pragma unroll
    for (int r = 0; r < 4; ++r) {
        float inv = 1.f / l_run[r];
        size_t row = (size_t)(b * SS + qt * 64 + w * 16 + lg * 4 + r);
        #pragma unroll
        for (int m = 0; m < 4; ++m)
            Q[row * (NQH * DD) + h * DD + m * 16 + l15] = f2bf(acc_o[m][r] * inv);
    }
}

// ---------------------------------------------------------------------------
extern "C" void kernel_launch(void* const* d_in, const int* in_sizes, int n_in,
                              void* d_out, int out_size, void* d_ws, size_t ws_size,
                              hipStream_t stream)
{
    const float* X  = (const float*)d_in[0];
    const float* Wq = (const float*)d_in[1];
    const float* Wk = (const float*)d_in[2];
    const float* Wv = (const float*)d_in[3];
    const float* Wo = (const float*)d_in[4];
    float* out = (float*)d_out;

    // workspace carve (bytes):
    char* ws = (char*)d_ws;
    unsigned short* Xbf  = (unsigned short*)(ws);                       // 8192x2048   (33.5 MB)
    unsigned short* WqT  = (unsigned short*)(ws + 33554432);            // 2048x2048   (8.4 MB) — reused for WoT
    unsigned short* WkvT = (unsigned short*)(ws + 41943040);            // 1024x2048   (4.2 MB)
    unsigned short* Qbf  = (unsigned short*)(ws + 46137344);            // 8192x2048   (33.5 MB) — also attn out
    unsigned short* KVbf = (unsigned short*)(ws + 79691776);            // 8192x1024   (16.8 MB)
    // total 96.5 MB

    dim3 blk(256);

    // convert X, transpose+convert Wq / Wk / Wv
    conv_bf16<<<(MROWS * HH / 8 + 255) / 256, blk, 0, stream>>>(X, Xbf, MROWS * HH / 8);
    transpose_conv<<<dim3(HH / 64, HH / 64), blk, 0, stream>>>(Wq, WqT, HH, NQH * DD);
    transpose_conv<<<dim3((NKVH * DD) / 64, HH / 64), blk, 0, stream>>>(Wk, WkvT, HH, NKVH * DD);
    transpose_conv<<<dim3((NKVH * DD) / 64, HH / 64), blk, 0, stream>>>(Wv, WkvT + (size_t)(NKVH * DD) * HH, HH, NKVH * DD);

    // projections: Q [8192][2048], K|V fused [8192][1024]
    gemm_bf16<unsigned short><<<dim3((NQH * DD) / 128, MROWS / 128), blk, 0, stream>>>(
        Xbf, WqT, Qbf, MROWS, NQH * DD, HH);
    gemm_bf16<unsigned short><<<dim3(1024 / 128, MROWS / 128), blk, 0, stream>>>(
        Xbf, WkvT, KVbf, MROWS, 1024, HH);

    rope_bf16<<<(MROWS * NQH * 32 + MROWS * NKVH * 32) / 256, blk, 0, stream>>>(Qbf, KVbf);

    attn_bf16<<<dim3(SS / 64, NQH, BB), blk, 0, stream>>>(Qbf, KVbf);

    // Wo transpose (reuses WqT buffer — safe, gemm_Q already consumed it) + output GEMM (fp32 out)
    transpose_conv<<<dim3(HH / 64, HH / 64), blk, 0, stream>>>(Wo, WqT, NQH * DD, HH);
    gemm_bf16<float><<<dim3(HH / 128, MROWS / 128), blk, 0, stream>>>(
        Qbf, WqT, out, MROWS, HH, NQH * DD);
}

// Round 3
// 660.516 us; speedup vs baseline: 5.0109x; 1.2530x over previous
//
#include <hip/hip_runtime.h>
#include <math.h>

#define BB 8
#define SS 1024
#define HH 2048
#define NQH 32
#define NKVH 8
#define DD 64
#define MROWS (BB*SS)   // 8192

typedef __attribute__((ext_vector_type(8))) short bf16x8;   // 8 bf16 in 4 VGPRs
typedef __attribute__((ext_vector_type(4))) float f32x4;

__device__ __forceinline__ unsigned short f2bf(float x) {
    unsigned int u = __float_as_uint(x);
    unsigned int r = (u + 0x7FFFu + ((u >> 16) & 1u)) >> 16;   // RNE
    return (unsigned short)r;
}
__device__ __forceinline__ float bf2f(unsigned short u) {
    return __uint_as_float(((unsigned int)u) << 16);
}

__device__ __forceinline__ void gload_lds16(const void* gsrc, void* ldst) {
    __builtin_amdgcn_global_load_lds(
        (const __attribute__((address_space(1))) unsigned int*)gsrc,
        (__attribute__((address_space(3))) unsigned int*)ldst,
        16, 0, 0);
}

// ---------------------------------------------------------------------------
// fp32 -> bf16 elementwise convert, 8 elements/thread
// ---------------------------------------------------------------------------
__global__ void conv_bf16(const float* __restrict__ src,
                          unsigned short* __restrict__ dst, int n8)
{
    int i = blockIdx.x * 256 + threadIdx.x;
    if (i >= n8) return;
    const float4* s4 = (const float4*)src;
    float4 a = s4[i * 2], b = s4[i * 2 + 1];
    bf16x8 o;
    o[0] = (short)f2bf(a.x); o[1] = (short)f2bf(a.y);
    o[2] = (short)f2bf(a.z); o[3] = (short)f2bf(a.w);
    o[4] = (short)f2bf(b.x); o[5] = (short)f2bf(b.y);
    o[6] = (short)f2bf(b.z); o[7] = (short)f2bf(b.w);
    *(bf16x8*)(dst + (size_t)i * 8) = o;
}

// ---------------------------------------------------------------------------
// W [K][N] fp32  ->  WT [N][K] bf16  (64x64 tiles via LDS)
// ---------------------------------------------------------------------------
__global__ __launch_bounds__(256) void transpose_conv(
    const float* __restrict__ W, unsigned short* __restrict__ WT, int K, int N)
{
    __shared__ unsigned short t[64][68];
    const int bn = blockIdx.x * 64;   // W col tile = WT row tile
    const int bk = blockIdx.y * 64;   // W row tile
    #pragma unroll
    for (int it = 0; it < 4; ++it) {
        int idx = it * 256 + threadIdx.x;
        int r  = idx >> 4;            // k row 0..63
        int cq = (idx & 15) * 4;      // n col
        float4 v = *(const float4*)(W + (size_t)(bk + r) * N + bn + cq);
        t[cq + 0][r] = f2bf(v.x);
        t[cq + 1][r] = f2bf(v.y);
        t[cq + 2][r] = f2bf(v.z);
        t[cq + 3][r] = f2bf(v.w);
    }
    __syncthreads();
    #pragma unroll
    for (int it = 0; it < 4; ++it) {
        int idx = it * 256 + threadIdx.x;
        int r  = idx >> 4;            // n row 0..63
        int cq = (idx & 15) * 4;      // k col
        ushort4 o;
        o.x = t[r][cq + 0]; o.y = t[r][cq + 1];
        o.z = t[r][cq + 2]; o.w = t[r][cq + 3];
        *(ushort4*)(WT + (size_t)(bn + r) * K + bk + cq) = o;
    }
}

// ---------------------------------------------------------------------------
// bf16 MFMA GEMM (m97 structure): C[M,N] = A[M,K] * Bt[N,K]^T
// ---------------------------------------------------------------------------
template <typename OutT>
__global__ __launch_bounds__(256) void gemm_bf16(
    const unsigned short* __restrict__ A,    // [M][K] bf16
    const unsigned short* __restrict__ Bt,   // [N][K] bf16
    OutT* __restrict__ C, int M, int N, int K)
{
    __shared__ __align__(16) unsigned short As[128 * 32];
    __shared__ __align__(16) unsigned short Bs[128 * 32];
    const int tid = threadIdx.x;
    const int lane = tid & 63;
    const int w = tid >> 6;
    const int wr = w >> 1, wc = w & 1;
    const int l15 = lane & 15, lg = lane >> 4;
    const int bm = blockIdx.y * 128, bn = blockIdx.x * 128;

    f32x4 acc[4][4] = {};

    for (int k0 = 0; k0 < K; k0 += 32) {
        #pragma unroll
        for (int t = 0; t < 2; ++t) {
            int lin = t * 256 + tid;
            int row = lin >> 2, cg = lin & 3;
            gload_lds16(A  + (size_t)(bm + row) * K + k0 + cg * 8, As + (size_t)lin * 8);
            gload_lds16(Bt + (size_t)(bn + row) * K + k0 + cg * 8, Bs + (size_t)lin * 8);
        }
        __syncthreads();
        bf16x8 af[4], bfr[4];
        #pragma unroll
        for (int m = 0; m < 4; ++m)
            af[m] = *(const bf16x8*)(As + (wr * 64 + m * 16 + l15) * 32 + lg * 8);
        #pragma unroll
        for (int n = 0; n < 4; ++n)
            bfr[n] = *(const bf16x8*)(Bs + (wc * 64 + n * 16 + l15) * 32 + lg * 8);
        #pragma unroll
        for (int m = 0; m < 4; ++m)
            #pragma unroll
            for (int n = 0; n < 4; ++n)
                acc[m][n] = __builtin_amdgcn_mfma_f32_16x16x32_bf16(
                    af[m], bfr[n], acc[m][n], 0, 0, 0);
        __syncthreads();
    }

    #pragma unroll
    for (int m = 0; m < 4; ++m) {
        int row0 = bm + wr * 64 + m * 16 + lg * 4;
        #pragma unroll
        for (int n = 0; n < 4; ++n) {
            int col = bn + wc * 64 + n * 16 + l15;
            #pragma unroll
            for (int r = 0; r < 4; ++r) {
                float v = acc[m][n][r];
                if constexpr (sizeof(OutT) == 2)
                    C[(size_t)(row0 + r) * N + col] = (OutT)f2bf(v);
                else
                    C[(size_t)(row0 + r) * N + col] = v;
            }
        }
    }
}

// ---------------------------------------------------------------------------
// RoPE in-place, bf16.
// ---------------------------------------------------------------------------
__global__ void rope_bf16(unsigned short* __restrict__ Q,
                          unsigned short* __restrict__ KV)
{
    int idx = blockIdx.x * 256 + threadIdx.x;
    const int totQ = MROWS * NQH * 32;
    unsigned short* x;
    int j, pos;
    if (idx < totQ) {
        j = idx & 31;
        int hd = idx >> 5;                // row*32 + head
        x = Q + (size_t)hd * 64;
        pos = (hd >> 5) & (SS - 1);
    } else {
        idx -= totQ;
        j = idx & 31;
        int hd = idx >> 5;                // row*8 + head
        int row = hd >> 3, head = hd & 7;
        x = KV + (size_t)row * 1024 + head * 64;
        pos = row & (SS - 1);
    }
    float ang = (float)pos * __expf(-(float)j * 0.28782314f);  // ln(1e4)/32
    float s, c;
    __sincosf(ang, &s, &c);
    float x1 = bf2f(x[j]), x2 = bf2f(x[j + 32]);
    x[j]      = f2bf(x1 * c - x2 * s);
    x[j + 32] = f2bf(x2 * c + x1 * s);
}

// ---------------------------------------------------------------------------
// Causal GQA flash attention v2, bf16 MFMA, swapped QK^T.
// Grid (S/128, NQ, B) with qt reversed; 256 threads = 4 waves.
// Wave w owns 32 q-rows. KVBLK=64. S^T = mfma(K, Q): K,Q natural fragments;
// per-lane q col = l15, keys = m*16+lg*4+r -> 2-shuffle row reduce.
// V^T double-buffered in LDS (stride 88 shorts, 16B-aligned rows);
// prefetch issue-early / write-late (T14). One barrier per tile.
// P via per-wave LDS. Output in-place over Q.
// ---------------------------------------------------------------------------
#define VST 88   // LDS row stride in shorts (176B: 16B-aligned, conflict-spread)

__global__ __launch_bounds__(256) void attn_bf16(
    unsigned short* Q,                 // [B*S][2048], also output
    const unsigned short* KV)          // [B*S][1024]: 0-511 K, 512-1023 V
{
    const int qt = (int)gridDim.x - 1 - (int)blockIdx.x;   // big tiles first
    const int h = blockIdx.y, b = blockIdx.z;
    const int hk = h >> 2;
    const int tid = threadIdx.x;
    const int w = tid >> 6, lane = tid & 63;
    const int l15 = lane & 15, lg = lane >> 4;

    __shared__ __align__(16) unsigned short VT[2][64 * VST];   // [buf][d][key]
    __shared__ __align__(16) unsigned short Pl[4][32 * VST];   // per-wave [q][key]

    const int wq0 = qt * 128 + w * 32;        // wave's first q-row (seq-local)

    // Q B-fragments (held for whole kernel): qf[n][kk], q col = n*16+l15
    bf16x8 qf[2][2];
    #pragma unroll
    for (int n = 0; n < 2; ++n)
        #pragma unroll
        for (int kk = 0; kk < 2; ++kk)
            qf[n][kk] = *(const bf16x8*)(
                Q + (size_t)(b * SS + wq0 + n * 16 + l15) * 2048 + h * 64 + kk * 32 + lg * 8);

    f32x4 acc[2][4] = {};     // [mq: q-frag][n: d-frag], row=q=lg*4+r, col=d=n*16+l15
    float m_run[2], l_run[2]; // per q = n*16 + l15
    #pragma unroll
    for (int n = 0; n < 2; ++n) { m_run[n] = -INFINITY; l_run[n] = 0.f; }

    const int nkt = 2 * qt + 2;

    // initial V^T stage (kt=0): thread handles key=lane, d = w*16 .. +15
    {
        const unsigned short* vrow =
            KV + (size_t)(b * SS + lane) * 1024 + 512 + hk * 64 + w * 16;
        bf16x8 v0 = *(const bf16x8*)vrow;
        bf16x8 v1 = *(const bf16x8*)(vrow + 8);
        #pragma unroll
        for (int i = 0; i < 8; ++i) {
            VT[0][(w * 16 + i) * VST + lane]     = (unsigned short)v0[i];
            VT[0][(w * 16 + 8 + i) * VST + lane] = (unsigned short)v1[i];
        }
    }
    __syncthreads();

    for (int kt = 0; kt < nkt; ++kt) {
        const int cur = kt & 1;
        const bool pf = (kt + 1 < nkt);
        bf16x8 vp0, vp1;
        if (pf) {   // issue next V tile loads early; write to LDS after PV
            const unsigned short* vrow =
                KV + (size_t)(b * SS + (kt + 1) * 64 + lane) * 1024 + 512 + hk * 64 + w * 16;
            vp0 = *(const bf16x8*)vrow;
            vp1 = *(const bf16x8*)(vrow + 8);
        }

        // S^T = K Q : A = K natural rows, B = Q natural rows
        const unsigned short* kbase = KV + (size_t)(b * SS + kt * 64) * 1024 + hk * 64;
        f32x4 sa[4][2] = {};   // [m: key-frag][n: q-frag]
        #pragma unroll
        for (int m = 0; m < 4; ++m) {
            #pragma unroll
            for (int kk = 0; kk < 2; ++kk) {
                bf16x8 kf = *(const bf16x8*)(
                    kbase + (size_t)(m * 16 + l15) * 1024 + kk * 32 + lg * 8);
                sa[m][0] = __builtin_amdgcn_mfma_f32_16x16x32_bf16(kf, qf[0][kk], sa[m][0], 0, 0, 0);
                sa[m][1] = __builtin_amdgcn_mfma_f32_16x16x32_bf16(kf, qf[1][kk], sa[m][1], 0, 0, 0);
            }
        }

        // online softmax: lane owns q = n*16+l15 (n=0,1), keys = m*16+lg*4+r
        float corr[2];
        #pragma unroll
        for (int n = 0; n < 2; ++n) {
            const int qg = wq0 + n * 16 + l15;
            float sv[4][4];
            float mx = -INFINITY;
            #pragma unroll
            for (int m = 0; m < 4; ++m)
                #pragma unroll
                for (int r = 0; r < 4; ++r) {
                    int keyg = kt * 64 + m * 16 + lg * 4 + r;
                    float v = sa[m][n][r] * 0.125f;           // 1/sqrt(64)
                    v = (keyg > qg) ? -INFINITY : v;          // causal
                    sv[m][r] = v;
                    mx = fmaxf(mx, v);
                }
            mx = fmaxf(mx, __shfl_xor(mx, 16));
            mx = fmaxf(mx, __shfl_xor(mx, 32));
            float mnew = fmaxf(m_run[n], mx);
            corr[n] = __expf(m_run[n] - mnew);
            float ps = 0.f;
            #pragma unroll
            for (int m = 0; m < 4; ++m)
                #pragma unroll
                for (int r = 0; r < 4; ++r) {
                    float p = __expf(sv[m][r] - mnew);
                    ps += p;
                    Pl[w][(n * 16 + l15) * VST + kt * 0 + m * 16 + lg * 4 + r] = f2bf(p);
                }
            ps += __shfl_xor(ps, 16);
            ps += __shfl_xor(ps, 32);
            l_run[n] = l_run[n] * corr[n] + ps;
            m_run[n] = mnew;
        }

        // rescale O: row q = mq*16 + lg*4 + r; stats live in lane lg*4+r (frag mq)
        #pragma unroll
        for (int mq = 0; mq < 2; ++mq)
            #pragma unroll
            for (int r = 0; r < 4; ++r) {
                float cb = __shfl(corr[mq], lg * 4 + r);
                #pragma unroll
                for (int n = 0; n < 4; ++n) acc[mq][n][r] *= cb;
            }

        // O += P V : A = P rows (wave LDS), B = V^T rows (shared LDS)
        #pragma unroll
        for (int kk = 0; kk < 2; ++kk) {
            bf16x8 pa0 = *(const bf16x8*)(&Pl[w][(l15) * VST + kk * 32 + lg * 8]);
            bf16x8 pa1 = *(const bf16x8*)(&Pl[w][(16 + l15) * VST + kk * 32 + lg * 8]);
            #pragma unroll
            for (int n = 0; n < 4; ++n) {
                bf16x8 vb = *(const bf16x8*)(&VT[cur][(n * 16 + l15) * VST + kk * 32 + lg * 8]);
                acc[0][n] = __builtin_amdgcn_mfma_f32_16x16x32_bf16(pa0, vb, acc[0][n], 0, 0, 0);
                acc[1][n] = __builtin_amdgcn_mfma_f32_16x16x32_bf16(pa1, vb, acc[1][n], 0, 0, 0);
            }
        }

        // write prefetched V tile into the other buffer (safe: its last readers
        // finished before the barrier that ended iteration kt-1)
        if (pf) {
            #pragma unroll
            for (int i = 0; i < 8; ++i) {
                VT[cur ^ 1][(w * 16 + i) * VST + lane]     = (unsigned short)vp0[i];
                VT[cur ^ 1][(w * 16 + 8 + i) * VST + lane] = (unsigned short)vp1[i];
            }
        }
        __syncthreads();
    }

    // epilogue: O = acc / l, in-place over Q
    float invl[2];
    #pragma unroll
    for (int n = 0; n < 2; ++n) invl[n] = 1.f / l_run[n];
    #pragma unroll
    for (int mq = 0; mq < 2; ++mq)
        #pragma unroll
        for (int r = 0; r < 4; ++r) {
            float ib = __shfl(invl[mq], lg * 4 + r);
            int qrow = wq0 + mq * 16 + lg * 4 + r;
            unsigned short* orow = Q + (size_t)(b * SS + qrow) * 2048 + h * 64;
            #pragma unroll
            for (int n = 0; n < 4; ++n)
                orow[n * 16 + l15] = f2bf(acc[mq][n][r] * ib);
        }
}

// ---------------------------------------------------------------------------
extern "C" void kernel_launch(void* const* d_in, const int* in_sizes, int n_in,
                              void* d_out, int out_size, void* d_ws, size_t ws_size,
                              hipStream_t stream)
{
    const float* X  = (const float*)d_in[0];
    const float* Wq = (const float*)d_in[1];
    const float* Wk = (const float*)d_in[2];
    const float* Wv = (const float*)d_in[3];
    const float* Wo = (const float*)d_in[4];
    float* out = (float*)d_out;

    char* ws = (char*)d_ws;
    unsigned short* Xbf  = (unsigned short*)(ws);                       // 8192x2048
    unsigned short* WqT  = (unsigned short*)(ws + 33554432);            // 2048x2048 (reused for WoT)
    unsigned short* WkvT = (unsigned short*)(ws + 41943040);            // 1024x2048
    unsigned short* Qbf  = (unsigned short*)(ws + 46137344);            // 8192x2048 (also attn out)
    unsigned short* KVbf = (unsigned short*)(ws + 79691776);            // 8192x1024

    dim3 blk(256);

    conv_bf16<<<(MROWS * HH / 8 + 255) / 256, blk, 0, stream>>>(X, Xbf, MROWS * HH / 8);
    transpose_conv<<<dim3(HH / 64, HH / 64), blk, 0, stream>>>(Wq, WqT, HH, NQH * DD);
    transpose_conv<<<dim3((NKVH * DD) / 64, HH / 64), blk, 0, stream>>>(Wk, WkvT, HH, NKVH * DD);
    transpose_conv<<<dim3((NKVH * DD) / 64, HH / 64), blk, 0, stream>>>(Wv, WkvT + (size_t)(NKVH * DD) * HH, HH, NKVH * DD);

    gemm_bf16<unsigned short><<<dim3((NQH * DD) / 128, MROWS / 128), blk, 0, stream>>>(
        Xbf, WqT, Qbf, MROWS, NQH * DD, HH);
    gemm_bf16<unsigned short><<<dim3(1024 / 128, MROWS / 128), blk, 0, stream>>>(
        Xbf, WkvT, KVbf, MROWS, 1024, HH);

    rope_bf16<<<(MROWS * NQH * 32 + MROWS * NKVH * 32) / 256, blk, 0, stream>>>(Qbf, KVbf);

    attn_bf16<<<dim3(SS / 128, NQH, BB), blk, 0, stream>>>(Qbf, KVbf);

    transpose_conv<<<dim3(HH / 64, HH / 64), blk, 0, stream>>>(Wo, WqT, NQH * DD, HH);
    gemm_bf16<float><<<dim3(HH / 128, MROWS / 128), blk, 0, stream>>>(
        Qbf, WqT, out, MROWS, HH, NQH * DD);
}

// Round 4
// 589.255 us; speedup vs baseline: 5.6169x; 1.1209x over previous
//
#include <hip/hip_runtime.h>
#include <math.h>

#define BB 8
#define SS 1024
#define HH 2048
#define NQH 32
#define NKVH 8
#define DD 64
#define MROWS (BB*SS)   // 8192
#define QKVN 3072       // fused QKV row width (Q 0-2047 | K 2048-2559 | V 2560-3071)

typedef __attribute__((ext_vector_type(8))) short bf16x8;
typedef __attribute__((ext_vector_type(4))) float f32x4;
typedef __attribute__((ext_vector_type(16))) float f32x16;
typedef __attribute__((ext_vector_type(4))) unsigned int u32x4;

__device__ __forceinline__ unsigned short f2bf(float x) {
    unsigned int u = __float_as_uint(x);
    unsigned int r = (u + 0x7FFFu + ((u >> 16) & 1u)) >> 16;   // RNE
    return (unsigned short)r;
}
__device__ __forceinline__ float bf2f(unsigned short u) {
    return __uint_as_float(((unsigned int)u) << 16);
}

__device__ __forceinline__ void gload_lds16(const void* gsrc, void* ldst) {
    __builtin_amdgcn_global_load_lds(
        (const __attribute__((address_space(1))) unsigned int*)gsrc,
        (__attribute__((address_space(3))) unsigned int*)ldst,
        16, 0, 0);
}

// ---------------------------------------------------------------------------
// fp32 -> bf16 elementwise convert, 8 elements/thread
// ---------------------------------------------------------------------------
__global__ void conv_bf16(const float* __restrict__ src,
                          unsigned short* __restrict__ dst, int n8)
{
    int i = blockIdx.x * 256 + threadIdx.x;
    if (i >= n8) return;
    const float4* s4 = (const float4*)src;
    float4 a = s4[i * 2], b = s4[i * 2 + 1];
    bf16x8 o;
    o[0] = (short)f2bf(a.x); o[1] = (short)f2bf(a.y);
    o[2] = (short)f2bf(a.z); o[3] = (short)f2bf(a.w);
    o[4] = (short)f2bf(b.x); o[5] = (short)f2bf(b.y);
    o[6] = (short)f2bf(b.z); o[7] = (short)f2bf(b.w);
    *(bf16x8*)(dst + (size_t)i * 8) = o;
}

// ---------------------------------------------------------------------------
// W [K][N] fp32  ->  WT [N][K] bf16  (64x64 tiles via LDS)
// ---------------------------------------------------------------------------
__global__ __launch_bounds__(256) void transpose_conv(
    const float* __restrict__ W, unsigned short* __restrict__ WT, int K, int N)
{
    __shared__ unsigned short t[64][68];
    const int bn = blockIdx.x * 64;
    const int bk = blockIdx.y * 64;
    #pragma unroll
    for (int it = 0; it < 4; ++it) {
        int idx = it * 256 + threadIdx.x;
        int r  = idx >> 4;
        int cq = (idx & 15) * 4;
        float4 v = *(const float4*)(W + (size_t)(bk + r) * N + bn + cq);
        t[cq + 0][r] = f2bf(v.x);
        t[cq + 1][r] = f2bf(v.y);
        t[cq + 2][r] = f2bf(v.z);
        t[cq + 3][r] = f2bf(v.w);
    }
    __syncthreads();
    #pragma unroll
    for (int it = 0; it < 4; ++it) {
        int idx = it * 256 + threadIdx.x;
        int r  = idx >> 4;
        int cq = (idx & 15) * 4;
        ushort4 o;
        o.x = t[r][cq + 0]; o.y = t[r][cq + 1];
        o.z = t[r][cq + 2]; o.w = t[r][cq + 3];
        *(ushort4*)(WT + (size_t)(bn + r) * K + bk + cq) = o;
    }
}

// ---------------------------------------------------------------------------
// bf16 MFMA GEMM (m97 structure): C = A[M,K](lda) * Bt[N,K](ldb)^T -> C(ldc)
// 128x128 tile, BK=32, 4 waves, 4x4 16x16x32 fragments, fp32 accum.
// ---------------------------------------------------------------------------
template <typename OutT>
__global__ __launch_bounds__(256) void gemm_bf16(
    const unsigned short* __restrict__ A,  int lda,
    const unsigned short* __restrict__ Bt, int ldb,
    OutT* __restrict__ C, int ldc, int K)
{
    __shared__ __align__(16) unsigned short As[128 * 32];
    __shared__ __align__(16) unsigned short Bs[128 * 32];
    const int tid = threadIdx.x;
    const int lane = tid & 63;
    const int w = tid >> 6;
    const int wr = w >> 1, wc = w & 1;
    const int l15 = lane & 15, lg = lane >> 4;
    const int bm = blockIdx.y * 128, bn = blockIdx.x * 128;

    f32x4 acc[4][4] = {};

    for (int k0 = 0; k0 < K; k0 += 32) {
        #pragma unroll
        for (int t = 0; t < 2; ++t) {
            int lin = t * 256 + tid;
            int row = lin >> 2, cg = lin & 3;
            gload_lds16(A  + (size_t)(bm + row) * lda + k0 + cg * 8, As + (size_t)lin * 8);
            gload_lds16(Bt + (size_t)(bn + row) * ldb + k0 + cg * 8, Bs + (size_t)lin * 8);
        }
        __syncthreads();
        bf16x8 af[4], bfr[4];
        #pragma unroll
        for (int m = 0; m < 4; ++m)
            af[m] = *(const bf16x8*)(As + (wr * 64 + m * 16 + l15) * 32 + lg * 8);
        #pragma unroll
        for (int n = 0; n < 4; ++n)
            bfr[n] = *(const bf16x8*)(Bs + (wc * 64 + n * 16 + l15) * 32 + lg * 8);
        #pragma unroll
        for (int m = 0; m < 4; ++m)
            #pragma unroll
            for (int n = 0; n < 4; ++n)
                acc[m][n] = __builtin_amdgcn_mfma_f32_16x16x32_bf16(
                    af[m], bfr[n], acc[m][n], 0, 0, 0);
        __syncthreads();
    }

    #pragma unroll
    for (int m = 0; m < 4; ++m) {
        int row0 = bm + wr * 64 + m * 16 + lg * 4;
        #pragma unroll
        for (int n = 0; n < 4; ++n) {
            int col = bn + wc * 64 + n * 16 + l15;
            #pragma unroll
            for (int r = 0; r < 4; ++r) {
                float v = acc[m][n][r];
                if constexpr (sizeof(OutT) == 2)
                    C[(size_t)(row0 + r) * ldc + col] = (OutT)f2bf(v);
                else
                    C[(size_t)(row0 + r) * ldc + col] = v;
            }
        }
    }
}

// ---------------------------------------------------------------------------
// RoPE in-place on fused QKV buffer [8192][3072].
// ---------------------------------------------------------------------------
__global__ void rope_bf16(unsigned short* __restrict__ QKV)
{
    int idx = blockIdx.x * 256 + threadIdx.x;
    const int totQ = MROWS * NQH * 32;
    unsigned short* x;
    int j, pos;
    if (idx < totQ) {
        j = idx & 31;
        int hd = idx >> 5;                // row*32 + head
        int row = hd >> 5, head = hd & 31;
        x = QKV + (size_t)row * QKVN + head * 64;
        pos = row & (SS - 1);
    } else {
        idx -= totQ;
        j = idx & 31;
        int hd = idx >> 5;                // row*8 + head
        int row = hd >> 3, head = hd & 7;
        x = QKV + (size_t)row * QKVN + 2048 + head * 64;
        pos = row & (SS - 1);
    }
    float ang = (float)pos * __expf(-(float)j * 0.28782314f);  // ln(1e4)/32
    float s, c;
    __sincosf(ang, &s, &c);
    float x1 = bf2f(x[j]), x2 = bf2f(x[j + 32]);
    x[j]      = f2bf(x1 * c - x2 * s);
    x[j + 32] = f2bf(x2 * c + x1 * s);
}

// ---------------------------------------------------------------------------
// Causal GQA flash attention v3: 32x32 MFMA + fully in-register softmax (T12).
// Grid (S/128, NQ, B) reversed qt; 256 threads = 4 waves; wave owns 32 q-rows.
// S^T = mfma(K, Q): lane owns q = lane&31 (32 keys in 16 regs, rest in lane^32)
//   -> row max/sum = reg reduce + 1 shfl_xor(32); m/l/corr lane-local scalars.
// P in registers via v_cvt_pk_bf16_f32 + v_permlane32_swap_b32.
// O^T = mfma(V^T, P): O cols = q = lane&31 -> rescale lane-local.
// V^T double-buffered in LDS (stride 72 shorts -> 2-way = free reads).
// Epilogue transposes O through reused LDS for coalesced stores (in-place on Q).
// ---------------------------------------------------------------------------
__global__ __launch_bounds__(256) void attn_bf16(unsigned short* QKV)
{
    const int qt = (int)gridDim.x - 1 - (int)blockIdx.x;   // heavy tiles first
    const int hh = blockIdx.y, b = blockIdx.z;
    const int hk = hh >> 2;
    const int tid = threadIdx.x;
    const int w = tid >> 6, lane = tid & 63;
    const int l31 = lane & 31, h32 = lane >> 5;

    __shared__ __align__(16) unsigned short VT[2][64 * 72];   // [buf][d][key]

    const int wq0 = qt * 128 + w * 32;
    const int qg  = wq0 + l31;            // this lane's q row

    // Q B-fragments: qf[kc] = Q[qg][kc*16 + 8*h32 .. +7]
    bf16x8 qf[4];
    {
        const unsigned short* qrow =
            QKV + (size_t)(b * SS + qg) * QKVN + hh * 64 + 8 * h32;
        #pragma unroll
        for (int kc = 0; kc < 4; ++kc)
            qf[kc] = *(const bf16x8*)(qrow + kc * 16);
    }

    f32x16 acc_o[2] = {};                 // O^T: row=d_local, col=q (lane-local)
    float m_run = -INFINITY, l_run = 0.f;

    const int nkt = 2 * qt + 2;

    // initial V^T stage (kt=0): thread: key=lane, d = w*16 .. +15
    {
        const unsigned short* vrow =
            QKV + (size_t)(b * SS + lane) * QKVN + 2560 + hk * 64 + w * 16;
        bf16x8 v0 = *(const bf16x8*)vrow;
        bf16x8 v1 = *(const bf16x8*)(vrow + 8);
        #pragma unroll
        for (int i = 0; i < 8; ++i) {
            VT[0][(w * 16 + i) * 72 + lane]     = (unsigned short)v0[i];
            VT[0][(w * 16 + 8 + i) * 72 + lane] = (unsigned short)v1[i];
        }
    }
    __syncthreads();

    for (int kt = 0; kt < nkt; ++kt) {
        const int cur = kt & 1;
        const bool pf = (kt + 1 < nkt);
        bf16x8 vp0, vp1;
        if (pf) {   // T14: issue next V tile loads early, LDS-write after PV
            const unsigned short* vrow =
                QKV + (size_t)(b * SS + (kt + 1) * 64 + lane) * QKVN + 2560 + hk * 64 + w * 16;
            vp0 = *(const bf16x8*)vrow;
            vp1 = *(const bf16x8*)(vrow + 8);
        }

        // S^T = K * Q  (A = K rows from global/L2, B = Q regs)
        f32x16 s[2] = {};   // [kh: key-half 0/1]
        {
            const unsigned short* kb =
                QKV + (size_t)(b * SS + kt * 64) * QKVN + 2048 + hk * 64 + 8 * h32;
            bf16x8 kf[2][4];
            #pragma unroll
            for (int kh = 0; kh < 2; ++kh)
                #pragma unroll
                for (int kc = 0; kc < 4; ++kc)
                    kf[kh][kc] = *(const bf16x8*)(kb + (size_t)(kh * 32 + l31) * QKVN + kc * 16);
            #pragma unroll
            for (int kh = 0; kh < 2; ++kh)
                #pragma unroll
                for (int kc = 0; kc < 4; ++kc)
                    s[kh] = __builtin_amdgcn_mfma_f32_32x32x16_bf16(
                        kf[kh][kc], qf[kc], s[kh], 0, 0, 0);
        }

        // scale + causal mask + row max (all lane-local; row = q = lane&31)
        const bool full = (kt * 64 + 63 <= wq0);   // wave-uniform
        float mx = -INFINITY;
        #pragma unroll
        for (int kh = 0; kh < 2; ++kh)
            #pragma unroll
            for (int r = 0; r < 16; ++r) {
                float v = s[kh][r] * 0.125f;       // 1/sqrt(64)
                if (!full) {
                    int keyg = kt * 64 + kh * 32 + (r & 3) + 8 * (r >> 2) + 4 * h32;
                    v = (keyg > qg) ? -INFINITY : v;
                }
                s[kh][r] = v;
                mx = fmaxf(mx, v);
            }
        mx = fmaxf(mx, __shfl_xor(mx, 32));
        const float mnew = fmaxf(m_run, mx);
        const float corr = __expf(m_run - mnew);
        float ps = 0.f;
        #pragma unroll
        for (int kh = 0; kh < 2; ++kh)
            #pragma unroll
            for (int r = 0; r < 16; ++r) {
                float p = __expf(s[kh][r] - mnew);
                s[kh][r] = p;
                ps += p;
            }
        ps += __shfl_xor(ps, 32);
        l_run = l_run * corr + ps;
        m_run = mnew;
        #pragma unroll
        for (int d0 = 0; d0 < 2; ++d0)
            #pragma unroll
            for (int r = 0; r < 16; ++r)
                acc_o[d0][r] *= corr;              // corr lane-local!

        // P -> bf16 PV fragments in-register (cvt_pk + permlane32_swap), then PV
        #pragma unroll
        for (int kh = 0; kh < 2; ++kh) {
            #pragma unroll
            for (int ks = 0; ks < 2; ++ks) {
                unsigned int w0, w1, w2, w3;
                asm("v_cvt_pk_bf16_f32 %0, %1, %2" : "=v"(w0) : "v"(s[kh][8*ks+0]), "v"(s[kh][8*ks+1]));
                asm("v_cvt_pk_bf16_f32 %0, %1, %2" : "=v"(w2) : "v"(s[kh][8*ks+4]), "v"(s[kh][8*ks+5]));
                asm("v_cvt_pk_bf16_f32 %0, %1, %2" : "=v"(w1) : "v"(s[kh][8*ks+2]), "v"(s[kh][8*ks+3]));
                asm("v_cvt_pk_bf16_f32 %0, %1, %2" : "=v"(w3) : "v"(s[kh][8*ks+6]), "v"(s[kh][8*ks+7]));
                asm("v_permlane32_swap_b32 %0, %1" : "+v"(w0), "+v"(w2));
                asm("v_permlane32_swap_b32 %0, %1" : "+v"(w1), "+v"(w3));
                union { u32x4 u; bf16x8 h; } pk;
                pk.u = (u32x4){w0, w1, w2, w3};
                #pragma unroll
                for (int d0 = 0; d0 < 2; ++d0) {
                    bf16x8 vb = *(const bf16x8*)(
                        &VT[cur][(d0 * 32 + l31) * 72 + kh * 32 + ks * 16 + 8 * h32]);
                    acc_o[d0] = __builtin_amdgcn_mfma_f32_32x32x16_bf16(
                        vb, pk.h, acc_o[d0], 0, 0, 0);
                }
            }
        }

        // write prefetched V tile into other buffer
        if (pf) {
            #pragma unroll
            for (int i = 0; i < 8; ++i) {
                VT[cur ^ 1][(w * 16 + i) * 72 + lane]     = (unsigned short)vp0[i];
                VT[cur ^ 1][(w * 16 + 8 + i) * 72 + lane] = (unsigned short)vp1[i];
            }
        }
        __syncthreads();
    }

    // epilogue: O^T -> O via LDS transpose (reuse VT; per-wave 32x72 slice)
    {
        unsigned short* ep = &VT[0][0] + w * (32 * 72);
        const float inv = 1.f / l_run;
        #pragma unroll
        for (int d0 = 0; d0 < 2; ++d0)
            #pragma unroll
            for (int r = 0; r < 16; ++r) {
                int d = d0 * 32 + (r & 3) + 8 * (r >> 2) + 4 * h32;
                ep[l31 * 72 + d] = f2bf(acc_o[d0][r] * inv);
            }
        __syncthreads();
        #pragma unroll
        for (int u = 0; u < 4; ++u) {
            int q = u * 8 + (lane >> 3);
            int c = lane & 7;
            *(bf16x8*)(QKV + (size_t)(b * SS + wq0 + q) * QKVN + hh * 64 + c * 8) =
                *(const bf16x8*)(ep + q * 72 + c * 8);
        }
    }
}

// ---------------------------------------------------------------------------
extern "C" void kernel_launch(void* const* d_in, const int* in_sizes, int n_in,
                              void* d_out, int out_size, void* d_ws, size_t ws_size,
                              hipStream_t stream)
{
    const float* X  = (const float*)d_in[0];
    const float* Wq = (const float*)d_in[1];
    const float* Wk = (const float*)d_in[2];
    const float* Wv = (const float*)d_in[3];
    const float* Wo = (const float*)d_in[4];
    float* out = (float*)d_out;

    char* ws = (char*)d_ws;
    unsigned short* Xbf    = (unsigned short*)(ws);               // 8192x2048  (33.55 MB)
    unsigned short* WqkvT  = (unsigned short*)(ws + 33554432);    // 3072x2048  (12.58 MB), reused for WoT
    unsigned short* QKV    = (unsigned short*)(ws + 46137344);    // 8192x3072  (50.33 MB)
    // total ~96.5 MB

    dim3 blk(256);

    conv_bf16<<<(MROWS * HH / 8 + 255) / 256, blk, 0, stream>>>(X, Xbf, MROWS * HH / 8);
    transpose_conv<<<dim3(2048 / 64, HH / 64), blk, 0, stream>>>(Wq, WqkvT, HH, 2048);
    transpose_conv<<<dim3(512 / 64,  HH / 64), blk, 0, stream>>>(Wk, WqkvT + (size_t)2048 * HH, HH, 512);
    transpose_conv<<<dim3(512 / 64,  HH / 64), blk, 0, stream>>>(Wv, WqkvT + (size_t)2560 * HH, HH, 512);

    // fused QKV projection: [8192][3072] = Xbf [8192][2048] @ WqkvT^T
    gemm_bf16<unsigned short><<<dim3(QKVN / 128, MROWS / 128), blk, 0, stream>>>(
        Xbf, HH, WqkvT, HH, QKV, QKVN, HH);

    rope_bf16<<<(MROWS * NQH * 32 + MROWS * NKVH * 32) / 256, blk, 0, stream>>>(QKV);

    attn_bf16<<<dim3(SS / 128, NQH, BB), blk, 0, stream>>>(QKV);

    // Wo^T into WqkvT buffer (free after QKV gemm), then output GEMM (fp32 out)
    transpose_conv<<<dim3(HH / 64, HH / 64), blk, 0, stream>>>(Wo, WqkvT, NQH * DD, HH);
    gemm_bf16<float><<<dim3(HH / 128, MROWS / 128), blk, 0, stream>>>(
        QKV, QKVN, WqkvT, HH, out, HH, NQH * DD);
}